// Round 11
// baseline (5308.893 us; speedup 1.0000x reference)
//
#include <hip/hip_runtime.h>
#include <cstdint>
#include <cstddef>

// Problem dims (fixed by reference)
#define WDIM 1024
#define BDIM 8
#define NDIM 1024
#define LDIM 12
#define HDIM 16
#define MROWS (BDIM * NDIM)   // 8192 token rows

using bf16x8 = __attribute__((ext_vector_type(8))) __bf16;
using f32x4  = __attribute__((ext_vector_type(4))) float;
using u32x4  = __attribute__((ext_vector_type(4))) uint32_t;
using u16x8  = __attribute__((ext_vector_type(8))) ushort;

static __device__ __forceinline__ f32x4 mfma16(bf16x8 a, bf16x8 b, f32x4 c) {
  return __builtin_amdgcn_mfma_f32_16x16x32_bf16(a, b, c, 0, 0, 0);
}

// fp32 -> bf16 round-to-nearest-even
static __device__ __forceinline__ ushort f2bf(float f) {
  uint32_t u = __builtin_bit_cast(uint32_t, f);
  u = (u + 0x7FFFu + ((u >> 16) & 1u)) >> 16;
  return (ushort)u;
}

static __device__ __forceinline__ uint32_t cvtpk(float lo, float hi) {
  uint32_t r;
  asm("v_cvt_pk_bf16_f32 %0, %1, %2" : "=v"(r) : "v"(lo), "v"(hi));
  return r;
}

// async global->LDS, 16B per lane; LDS dest must be wave-uniform base (lane*16 auto)
static __device__ __forceinline__ void g2lds16(const void* g, void* l) {
  __builtin_amdgcn_global_load_lds(
      (__attribute__((address_space(1))) void*)(g),
      (__attribute__((address_space(3))) void*)(l), 16, 0, 0);
}

// -------- LayerNorm: wave-per-row, 4 rows/block, no LDS, no barrier ----------
__global__ __launch_bounds__(256) void ln_kernel(const float* __restrict__ h,
                                                 const float* __restrict__ g,
                                                 const float* __restrict__ b,
                                                 ushort* __restrict__ out) {
  const int w = threadIdx.x >> 6, l = threadIdx.x & 63;
  const int row = blockIdx.x * 4 + w;
  const float4* rp = (const float4*)(h + (size_t)row * WDIM);
  float4 v[4];
  float s = 0.f, s2 = 0.f;
  #pragma unroll
  for (int j = 0; j < 4; ++j) {
    v[j] = rp[j * 64 + l];
    s  += v[j].x + v[j].y + v[j].z + v[j].w;
    s2 += v[j].x * v[j].x + v[j].y * v[j].y + v[j].z * v[j].z + v[j].w * v[j].w;
  }
  #pragma unroll
  for (int off = 32; off; off >>= 1) {
    s  += __shfl_xor(s, off);
    s2 += __shfl_xor(s2, off);
  }
  const float mu   = s * (1.0f / WDIM);
  const float var  = s2 * (1.0f / WDIM) - mu * mu;
  const float rstd = rsqrtf(var + 1e-5f);
  ushort4* op = (ushort4*)(out + (size_t)row * WDIM);
  #pragma unroll
  for (int j = 0; j < 4; ++j) {
    const float4 gv = ((const float4*)g)[j * 64 + l];
    const float4 bv = ((const float4*)b)[j * 64 + l];
    ushort4 o;
    o.x = f2bf((v[j].x - mu) * rstd * gv.x + bv.x);
    o.y = f2bf((v[j].y - mu) * rstd * gv.y + bv.y);
    o.z = f2bf((v[j].z - mu) * rstd * gv.z + bv.z);
    o.w = f2bf((v[j].w - mu) * rstd * gv.w + bv.w);
    op[j * 64 + l] = o;
  }
}

// ------------- weight transpose+convert: fp32 [K][N] -> bf16 [N][K] ----------
__global__ __launch_bounds__(256) void transpose_cvt(const float* __restrict__ in,
                                                     ushort* __restrict__ out,
                                                     int K, int N) {
  __shared__ float sm[32][33];
  const int n0 = blockIdx.x * 32, k0 = blockIdx.y * 32;
  const int tx = threadIdx.x, ty = threadIdx.y;  // block (32,8)
  #pragma unroll
  for (int j = 0; j < 4; ++j)
    sm[ty + j * 8][tx] = in[(size_t)(k0 + ty + j * 8) * N + n0 + tx];
  __syncthreads();
  #pragma unroll
  for (int j = 0; j < 4; ++j)
    out[(size_t)(n0 + ty + j * 8) * K + k0 + tx] = f2bf(sm[tx][ty + j * 8]);
}

// --------- V transpose: qkv [rows][3072] -> vT [b,h,d=64,N] (bf16) -----------
__global__ __launch_bounds__(256) void v_transpose(const ushort* __restrict__ qkv,
                                                   ushort* __restrict__ vT) {
  const int nb = blockIdx.x, bh = blockIdx.y;
  const int b = bh >> 4, h = bh & 15;
  const int tid = threadIdx.x;
  __shared__ ushort smT[64 * 64];
  const int n0 = nb * 64;
  const size_t rowb = (size_t)b * NDIM;
  #pragma unroll
  for (int p = 0; p < 2; ++p) {
    const int n  = p * 32 + (tid >> 3);
    const int d0 = (tid & 7) * 8;
    const uint4 vv = *(const uint4*)(qkv + (rowb + n0 + n) * 3072 + h * 192 + 128 + d0);
    const ushort* e = (const ushort*)&vv;
    const int key = d0;
    #pragma unroll
    for (int j = 0; j < 8; ++j)
      smT[(d0 + j) * 64 + (n ^ key)] = e[j];
  }
  __syncthreads();
  #pragma unroll
  for (int p = 0; p < 2; ++p) {
    const int d  = p * 32 + (tid >> 3);
    const int nc = (tid & 7) * 8;
    const int key = (d >> 3) << 3;
    const uint4 ov = *(const uint4*)&smT[d * 64 + (nc ^ key)];
    *(uint4*)(vT + ((size_t)bh * 64 + d) * NDIM + n0 + nc) = ov;
  }
}

// ============== 256x256 8-phase GEMM (all projections, opt split-K) ==========
// C[M,N] = A[M,Kfull] * Bt[N,Kfull]^T over K-slice [z*Kslice, (z+1)*Kslice).
// EPI_BF16/EPI_GELU: bias (+GELU) -> bf16 out (single slice only).
// EPI_RESA: fp32 residual atomicAdd of partial (bias added by z==0 slice).
enum { EPI_BF16 = 0, EPI_RESA = 1, EPI_GELU = 2 };

template <int EPI>
__global__ __launch_bounds__(512, 2) void gemm256_kernel(
    const ushort* __restrict__ A, const ushort* __restrict__ Bt,
    const float* __restrict__ bias, float* __restrict__ resid,
    ushort* __restrict__ outb, int M, int N, int Kfull, int Kslice) {
  __shared__ ushort smA[2 * 2 * 256 * 32];
  __shared__ ushort smB[2 * 2 * 256 * 32];
  const int tid = threadIdx.x;
  const int w = tid >> 6, l = tid & 63;
  const int lr = l & 15, lg = l >> 4;
  const int wm = w >> 2, wn = w & 3;

  const int z = blockIdx.z;
  const ushort* Ab  = A  + (size_t)z * Kslice;
  const ushort* Btb = Bt + (size_t)z * Kslice;

  const int gx = gridDim.x;
  const int nwg = gx * gridDim.y;
  const int id0 = blockIdx.y * gx + blockIdx.x;
  const int id = (id0 & 7) * (nwg >> 3) + (id0 >> 3);
  const int row0 = (id / gx) * 256, col0 = (id % gx) * 256;

  const int KT = Kslice >> 6;
  const int srow_l = l >> 2;
  const int scol = (((l & 3) ^ ((l >> 3) & 3)) * 8);
  const int ks = ((lg ^ ((lr >> 1) & 3)) * 8);

  f32x4 acc[8][4] = {};

  auto stageA = [&](int tau, int hh) {
    const int base = (((tau & 1) * 2 + hh) * 8192);
    const int colb = tau * 64 + hh * 32 + scol;
    #pragma unroll
    for (int j = 0; j < 2; ++j) {
      const int c = j * 8 + w;
      g2lds16(Ab + (size_t)(row0 + 16 * c + srow_l) * Kfull + colb, &smA[base + c * 512]);
    }
  };
  auto stageB = [&](int tau, int hh) {
    const int base = (((tau & 1) * 2 + hh) * 8192);
    const int colb = tau * 64 + hh * 32 + scol;
    #pragma unroll
    for (int j = 0; j < 2; ++j) {
      const int c = j * 8 + w;
      g2lds16(Btb + (size_t)(col0 + 16 * c + srow_l) * Kfull + colb, &smB[base + c * 512]);
    }
  };

  stageA(0, 0); stageB(0, 0);
  stageA(0, 1); stageB(0, 1);
  stageA(1, 0); stageB(1, 0);
  asm volatile("s_waitcnt vmcnt(8)" ::: "memory");
  __builtin_amdgcn_sched_barrier(0);
  __builtin_amdgcn_s_barrier();

  for (int tau = 0; tau < KT; ++tau) {
    const int ab0 = (tau & 1) * 16384;
    const int ab1 = ab0 + 8192;
    bf16x8 af[8], bf0, bf1;

    // ---- P1 ----
    #pragma unroll
    for (int m = 0; m < 8; ++m)
      af[m] = *(const bf16x8*)&smA[ab0 + (wm * 128 + m * 16 + lr) * 32 + ks];
    bf0 = *(const bf16x8*)&smB[ab0 + (wn * 64 + lr) * 32 + ks];
    bf1 = *(const bf16x8*)&smB[ab0 + (wn * 64 + 16 + lr) * 32 + ks];
    if (tau + 1 < KT) stageA(tau + 1, 1);
    __builtin_amdgcn_s_barrier();
    asm volatile("s_waitcnt lgkmcnt(0)" ::: "memory");
    __builtin_amdgcn_sched_barrier(0);
    __builtin_amdgcn_s_setprio(1);
    #pragma unroll
    for (int m = 0; m < 8; ++m) {
      acc[m][0] = mfma16(af[m], bf0, acc[m][0]);
      acc[m][1] = mfma16(af[m], bf1, acc[m][1]);
    }
    __builtin_amdgcn_s_setprio(0);
    __builtin_amdgcn_s_barrier();

    // ---- P2 ----
    bf0 = *(const bf16x8*)&smB[ab0 + (wn * 64 + 32 + lr) * 32 + ks];
    bf1 = *(const bf16x8*)&smB[ab0 + (wn * 64 + 48 + lr) * 32 + ks];
    if (tau + 1 < KT) stageB(tau + 1, 1);
    __builtin_amdgcn_s_barrier();
    asm volatile("s_waitcnt lgkmcnt(0)" ::: "memory");
    __builtin_amdgcn_sched_barrier(0);
    __builtin_amdgcn_s_setprio(1);
    #pragma unroll
    for (int m = 0; m < 8; ++m) {
      acc[m][2] = mfma16(af[m], bf0, acc[m][2]);
      acc[m][3] = mfma16(af[m], bf1, acc[m][3]);
    }
    __builtin_amdgcn_s_setprio(0);
    if (tau + 1 < KT) { asm volatile("s_waitcnt vmcnt(8)" ::: "memory"); }
    else              { asm volatile("s_waitcnt vmcnt(0)" ::: "memory"); }
    __builtin_amdgcn_sched_barrier(0);
    __builtin_amdgcn_s_barrier();

    // ---- P3 ----
    #pragma unroll
    for (int m = 0; m < 8; ++m)
      af[m] = *(const bf16x8*)&smA[ab1 + (wm * 128 + m * 16 + lr) * 32 + ks];
    bf0 = *(const bf16x8*)&smB[ab1 + (wn * 64 + lr) * 32 + ks];
    bf1 = *(const bf16x8*)&smB[ab1 + (wn * 64 + 16 + lr) * 32 + ks];
    if (tau + 2 < KT) { stageA(tau + 2, 0); stageB(tau + 2, 0); }
    __builtin_amdgcn_s_barrier();
    asm volatile("s_waitcnt lgkmcnt(0)" ::: "memory");
    __builtin_amdgcn_sched_barrier(0);
    __builtin_amdgcn_s_setprio(1);
    #pragma unroll
    for (int m = 0; m < 8; ++m) {
      acc[m][0] = mfma16(af[m], bf0, acc[m][0]);
      acc[m][1] = mfma16(af[m], bf1, acc[m][1]);
    }
    __builtin_amdgcn_s_setprio(0);
    __builtin_amdgcn_s_barrier();

    // ---- P4 ----
    bf0 = *(const bf16x8*)&smB[ab1 + (wn * 64 + 32 + lr) * 32 + ks];
    bf1 = *(const bf16x8*)&smB[ab1 + (wn * 64 + 48 + lr) * 32 + ks];
    __builtin_amdgcn_s_barrier();
    asm volatile("s_waitcnt lgkmcnt(0)" ::: "memory");
    __builtin_amdgcn_sched_barrier(0);
    __builtin_amdgcn_s_setprio(1);
    #pragma unroll
    for (int m = 0; m < 8; ++m) {
      acc[m][2] = mfma16(af[m], bf0, acc[m][2]);
      acc[m][3] = mfma16(af[m], bf1, acc[m][3]);
    }
    __builtin_amdgcn_s_setprio(0);
    if (tau + 2 < KT)      { asm volatile("s_waitcnt vmcnt(8)" ::: "memory"); }
    else if (tau + 1 < KT) { asm volatile("s_waitcnt vmcnt(4)" ::: "memory"); }
    __builtin_amdgcn_sched_barrier(0);
    __builtin_amdgcn_s_barrier();
  }

  #pragma unroll
  for (int m = 0; m < 8; ++m) {
    #pragma unroll
    for (int n = 0; n < 4; ++n) {
      #pragma unroll
      for (int i = 0; i < 4; ++i) {
        const int r = row0 + wm * 128 + m * 16 + lg * 4 + i;
        const int c = col0 + wn * 64 + n * 16 + lr;
        if constexpr (EPI == EPI_RESA) {
          const float v = acc[m][n][i] + (z == 0 ? bias[c] : 0.0f);
          atomicAdd(&resid[(size_t)r * N + c], v);
        } else {
          float v = acc[m][n][i] + bias[c];
          if constexpr (EPI == EPI_GELU) {
            v = 0.5f * v * (1.0f + erff(v * 0.70710678118f));
          }
          outb[(size_t)r * N + c] = f2bf(v);
        }
      }
    }
  }
}

// ------- fused attention: swapped QK^T, in-register P repack (no P-LDS) -------
__global__ __launch_bounds__(512) void attn_kernel(const ushort* __restrict__ qkv,
                                                   const ushort* __restrict__ vT,
                                                   ushort* __restrict__ out) {
  const int qb = blockIdx.x;
  const int bh = blockIdx.y;
  const int b = bh >> 4, h = bh & 15;
  const int tid = threadIdx.x;
  const int w = tid >> 6, l = tid & 63;
  const int lr = l & 15, lg = l >> 4;
  __shared__ ushort smK[2][64 * 64];
  __shared__ ushort smV[2][64 * 64];
  const int q0 = qb * 128 + w * 16;
  const size_t rowb = (size_t)b * NDIM;
  const ushort* vhead = vT + (size_t)bh * 64 * NDIM;  // [64][N]

  const u16x8 ob = {0x3F80, 0x3F80, 0x3F80, 0x3F80, 0x3F80, 0x3F80, 0x3F80, 0x3F80};
  const bf16x8 onesv = __builtin_bit_cast(bf16x8, ob);

  const int srow = l >> 3;
  const int skey = (srow & 3) ^ ((w & 1) << 2);
  const int scol = ((l & 7) ^ skey) * 8;
  const ushort* kg = qkv + (rowb + w * 8 + srow) * 3072 + h * 192 + 64 + scol;
  const ushort* vg = vhead + (size_t)(w * 8 + srow) * NDIM + scol;

  auto stage = [&](int buf, int kb) {
    g2lds16(kg + (size_t)kb * 64 * 3072, &smK[buf][w * 512]);
    g2lds16(vg + kb * 64,                &smV[buf][w * 512]);
  };

  bf16x8 qf0, qf1;
  {
    const ushort* qp = qkv + (rowb + q0 + lr) * 3072 + h * 192;
    qf0 = *(const bf16x8*)(qp + lg * 8);
    qf1 = *(const bf16x8*)(qp + 32 + lg * 8);
  }
  f32x4 o[4] = {};
  f32x4 lacc = {0.f, 0.f, 0.f, 0.f};

  const int rbase = (lr >> 2) * 8 + (lr & 3);
  const int kkey  = (lr & 3) ^ (((lr >> 2) & 1) << 2);
  const int vkey  = (lr & 3) ^ (((lr >> 3) & 1) << 2);
  const int kp0 = (lg ^ kkey) * 8, kp1 = ((4 + lg) ^ kkey) * 8;
  const int vp0 = (lg ^ vkey) * 8, vp1 = ((4 + lg) ^ vkey) * 8;

  stage(0, 0);
  int cur = 0;
  for (int kb = 0; kb < NDIM / 64; ++kb) {
    __syncthreads();
    if (kb + 1 < NDIM / 64) stage(cur ^ 1, kb + 1);

    f32x4 s[2][2];
    #pragma unroll
    for (int hh = 0; hh < 2; ++hh) {
      #pragma unroll
      for (int m = 0; m < 2; ++m) {
        const int r = hh * 32 + rbase + 4 * m;
        const ushort* kr = &smK[cur][r * 64];
        const bf16x8 kf0 = *(const bf16x8*)&kr[kp0];
        const bf16x8 kf1 = *(const bf16x8*)&kr[kp1];
        f32x4 z = {0.f, 0.f, 0.f, 0.f};
        s[hh][m] = mfma16(kf1, qf1, mfma16(kf0, qf0, z));
      }
    }

    bf16x8 pf[2];
    #pragma unroll
    for (int hh = 0; hh < 2; ++hh) {
      u32x4 pk;
      pk[0] = cvtpk(__expf(s[hh][0][0] * 0.125f), __expf(s[hh][0][1] * 0.125f));
      pk[1] = cvtpk(__expf(s[hh][0][2] * 0.125f), __expf(s[hh][0][3] * 0.125f));
      pk[2] = cvtpk(__expf(s[hh][1][0] * 0.125f), __expf(s[hh][1][1] * 0.125f));
      pk[3] = cvtpk(__expf(s[hh][1][2] * 0.125f), __expf(s[hh][1][3] * 0.125f));
      pf[hh] = __builtin_bit_cast(bf16x8, pk);
    }

    lacc = mfma16(pf[0], onesv, mfma16(pf[1], onesv, lacc));
    #pragma unroll
    for (int dt = 0; dt < 4; ++dt) {
      const ushort* vrow = &smV[cur][(dt * 16 + lr) * 64];
      const bf16x8 vf0 = *(const bf16x8*)&vrow[vp0];
      const bf16x8 vf1 = *(const bf16x8*)&vrow[vp1];
      o[dt] = mfma16(pf[0], vf0, mfma16(pf[1], vf1, o[dt]));
    }
    cur ^= 1;
  }

  #pragma unroll
  for (int i = 0; i < 4; ++i) {
    const float inv = 1.0f / lacc[i];
    const size_t orow = (rowb + q0 + lg * 4 + i) * (size_t)WDIM;
    #pragma unroll
    for (int dt = 0; dt < 4; ++dt)
      out[orow + h * 64 + dt * 16 + lr] = f2bf(o[dt][i] * inv);
  }
}

// ------------------------------- launcher ------------------------------------
extern "C" void kernel_launch(void* const* d_in, const int* in_sizes, int n_in,
                              void* d_out, int out_size, void* d_ws, size_t ws_size,
                              hipStream_t stream) {
  const float* x     = (const float*)d_in[0];
  const float* ln1_g = (const float*)d_in[1];
  const float* ln1_b = (const float*)d_in[2];
  const float* w_qkv = (const float*)d_in[3];
  const float* b_qkv = (const float*)d_in[4];
  const float* w_o   = (const float*)d_in[5];
  const float* b_o   = (const float*)d_in[6];
  const float* ln2_g = (const float*)d_in[7];
  const float* ln2_b = (const float*)d_in[8];
  const float* w_fc  = (const float*)d_in[9];
  const float* b_fc  = (const float*)d_in[10];
  const float* w_pr  = (const float*)d_in[11];
  const float* b_pr  = (const float*)d_in[12];

  float* hbuf = (float*)d_out;  // fp32 residual stream lives in d_out

  uint8_t* p = (uint8_t*)d_ws;
  ushort* wqkv_t = (ushort*)p; p += (size_t)3072 * 1024 * 2;
  ushort* wo_t   = (ushort*)p; p += (size_t)1024 * 1024 * 2;
  ushort* wfc_t  = (ushort*)p; p += (size_t)4096 * 1024 * 2;
  ushort* wpr_t  = (ushort*)p; p += (size_t)1024 * 4096 * 2;
  ushort* lnb    = (ushort*)p; p += (size_t)MROWS * 1024 * 2;
  ushort* qkvb   = (ushort*)p; p += (size_t)MROWS * 3072 * 2;
  ushort* attnb  = (ushort*)p; p += (size_t)MROWS * 1024 * 2;
  ushort* mlpb   = (ushort*)p; p += (size_t)MROWS * 4096 * 2;
  ushort* vTb    = (ushort*)p; p += (size_t)BDIM * HDIM * 64 * NDIM * 2;

  hipMemcpyAsync(hbuf, x, (size_t)MROWS * WDIM * sizeof(float),
                 hipMemcpyDeviceToDevice, stream);

  for (int l = 0; l < LDIM; ++l) {
    // ---- attention half ----
    ln_kernel<<<MROWS / 4, 256, 0, stream>>>(hbuf, ln1_g + l * 1024, ln1_b + l * 1024, lnb);
    transpose_cvt<<<dim3(96, 32), dim3(32, 8), 0, stream>>>(
        w_qkv + (size_t)l * 1024 * 3072, wqkv_t, 1024, 3072);
    gemm256_kernel<EPI_BF16><<<dim3(12, 32, 1), 512, 0, stream>>>(
        lnb, wqkv_t, b_qkv + (size_t)l * 3072, nullptr, qkvb, MROWS, 3072, 1024, 1024);
    v_transpose<<<dim3(16, 128), 256, 0, stream>>>(qkvb, vTb);
    attn_kernel<<<dim3(8, 128), 512, 0, stream>>>(qkvb, vTb, attnb);
    transpose_cvt<<<dim3(32, 32), dim3(32, 8), 0, stream>>>(
        w_o + (size_t)l * 1024 * 1024, wo_t, 1024, 1024);
    gemm256_kernel<EPI_RESA><<<dim3(4, 32, 2), 512, 0, stream>>>(
        attnb, wo_t, b_o + (size_t)l * 1024, hbuf, nullptr, MROWS, 1024, 1024, 512);
    // ---- MLP half ----
    ln_kernel<<<MROWS / 4, 256, 0, stream>>>(hbuf, ln2_g + l * 1024, ln2_b + l * 1024, lnb);
    transpose_cvt<<<dim3(128, 32), dim3(32, 8), 0, stream>>>(
        w_fc + (size_t)l * 1024 * 4096, wfc_t, 1024, 4096);
    gemm256_kernel<EPI_GELU><<<dim3(16, 32, 1), 512, 0, stream>>>(
        lnb, wfc_t, b_fc + (size_t)l * 4096, nullptr, mlpb, MROWS, 4096, 1024, 1024);
    transpose_cvt<<<dim3(32, 128), dim3(32, 8), 0, stream>>>(
        w_pr + (size_t)l * 4096 * 1024, wpr_t, 4096, 1024);
    gemm256_kernel<EPI_RESA><<<dim3(4, 32, 2), 512, 0, stream>>>(
        mlpb, wpr_t, b_pr + (size_t)l * 1024, hbuf, nullptr, MROWS, 1024, 4096, 2048);
  }
}

// Round 12
// 4622.221 us; speedup vs baseline: 1.1486x; 1.1486x over previous
//
#include <hip/hip_runtime.h>
#include <cstdint>
#include <cstddef>

// Problem dims (fixed by reference)
#define WDIM 1024
#define BDIM 8
#define NDIM 1024
#define LDIM 12
#define HDIM 16
#define MROWS (BDIM * NDIM)   // 8192 token rows

using bf16x8 = __attribute__((ext_vector_type(8))) __bf16;
using f32x4  = __attribute__((ext_vector_type(4))) float;
using u32x4  = __attribute__((ext_vector_type(4))) uint32_t;
using u16x8  = __attribute__((ext_vector_type(8))) ushort;

static __device__ __forceinline__ f32x4 mfma16(bf16x8 a, bf16x8 b, f32x4 c) {
  return __builtin_amdgcn_mfma_f32_16x16x32_bf16(a, b, c, 0, 0, 0);
}

// fp32 -> bf16 round-to-nearest-even
static __device__ __forceinline__ ushort f2bf(float f) {
  uint32_t u = __builtin_bit_cast(uint32_t, f);
  u = (u + 0x7FFFu + ((u >> 16) & 1u)) >> 16;
  return (ushort)u;
}

static __device__ __forceinline__ uint32_t cvtpk(float lo, float hi) {
  uint32_t r;
  asm("v_cvt_pk_bf16_f32 %0, %1, %2" : "=v"(r) : "v"(lo), "v"(hi));
  return r;
}

// async global->LDS, 16B per lane; LDS dest must be wave-uniform base (lane*16 auto)
static __device__ __forceinline__ void g2lds16(const void* g, void* l) {
  __builtin_amdgcn_global_load_lds(
      (__attribute__((address_space(1))) void*)(g),
      (__attribute__((address_space(3))) void*)(l), 16, 0, 0);
}

// -------- LayerNorm: wave-per-row, 4 rows/block, no LDS, no barrier ----------
__global__ __launch_bounds__(256) void ln_kernel(const float* __restrict__ h,
                                                 const float* __restrict__ g,
                                                 const float* __restrict__ b,
                                                 ushort* __restrict__ out) {
  const int w = threadIdx.x >> 6, l = threadIdx.x & 63;
  const int row = blockIdx.x * 4 + w;
  const float4* rp = (const float4*)(h + (size_t)row * WDIM);
  float4 v[4];
  float s = 0.f, s2 = 0.f;
  #pragma unroll
  for (int j = 0; j < 4; ++j) {
    v[j] = rp[j * 64 + l];
    s  += v[j].x + v[j].y + v[j].z + v[j].w;
    s2 += v[j].x * v[j].x + v[j].y * v[j].y + v[j].z * v[j].z + v[j].w * v[j].w;
  }
  #pragma unroll
  for (int off = 32; off; off >>= 1) {
    s  += __shfl_xor(s, off);
    s2 += __shfl_xor(s2, off);
  }
  const float mu   = s * (1.0f / WDIM);
  const float var  = s2 * (1.0f / WDIM) - mu * mu;
  const float rstd = rsqrtf(var + 1e-5f);
  ushort4* op = (ushort4*)(out + (size_t)row * WDIM);
  #pragma unroll
  for (int j = 0; j < 4; ++j) {
    const float4 gv = ((const float4*)g)[j * 64 + l];
    const float4 bv = ((const float4*)b)[j * 64 + l];
    ushort4 o;
    o.x = f2bf((v[j].x - mu) * rstd * gv.x + bv.x);
    o.y = f2bf((v[j].y - mu) * rstd * gv.y + bv.y);
    o.z = f2bf((v[j].z - mu) * rstd * gv.z + bv.z);
    o.w = f2bf((v[j].w - mu) * rstd * gv.w + bv.w);
    op[j * 64 + l] = o;
  }
}

// ------------- weight transpose+convert: fp32 [K][N] -> bf16 [N][K] ----------
__global__ __launch_bounds__(256) void transpose_cvt(const float* __restrict__ in,
                                                     ushort* __restrict__ out,
                                                     int K, int N) {
  __shared__ float sm[32][33];
  const int n0 = blockIdx.x * 32, k0 = blockIdx.y * 32;
  const int tx = threadIdx.x, ty = threadIdx.y;  // block (32,8)
  #pragma unroll
  for (int j = 0; j < 4; ++j)
    sm[ty + j * 8][tx] = in[(size_t)(k0 + ty + j * 8) * N + n0 + tx];
  __syncthreads();
  #pragma unroll
  for (int j = 0; j < 4; ++j)
    out[(size_t)(n0 + ty + j * 8) * K + k0 + tx] = f2bf(sm[tx][ty + j * 8]);
}

// ============== 256x256 8-phase GEMM (QKV / FC) ==============================
// EPI_BF16/EPI_GELU: bias (+GELU) -> bf16 out.
// EPI_QKV: bias -> Q/K columns to qkvb, V columns transposed into vT[bh][d][N]
//          (v_transpose kernel fused away; V never written to qkvb).
enum { EPI_BF16 = 0, EPI_QKV = 1, EPI_GELU = 2 };

template <int EPI>
__global__ __launch_bounds__(512, 2) void gemm256_kernel(
    const ushort* __restrict__ A, const ushort* __restrict__ Bt,
    const float* __restrict__ bias, ushort* __restrict__ vT,
    ushort* __restrict__ outb, int M, int N, int K) {
  __shared__ ushort smA[2 * 2 * 256 * 32];
  __shared__ ushort smB[2 * 2 * 256 * 32];
  const int tid = threadIdx.x;
  const int w = tid >> 6, l = tid & 63;
  const int lr = l & 15, lg = l >> 4;
  const int wm = w >> 2, wn = w & 3;

  const int gx = gridDim.x;
  const int nwg = gx * gridDim.y;
  const int id0 = blockIdx.y * gx + blockIdx.x;
  const int id = (id0 & 7) * (nwg >> 3) + (id0 >> 3);
  const int row0 = (id / gx) * 256, col0 = (id % gx) * 256;

  const int KT = K >> 6;
  const int srow_l = l >> 2;
  const int scol = (((l & 3) ^ ((l >> 3) & 3)) * 8);
  const int ks = ((lg ^ ((lr >> 1) & 3)) * 8);

  f32x4 acc[8][4] = {};

  auto stageA = [&](int tau, int hh) {
    const int base = (((tau & 1) * 2 + hh) * 8192);
    const int colb = tau * 64 + hh * 32 + scol;
    #pragma unroll
    for (int j = 0; j < 2; ++j) {
      const int c = j * 8 + w;
      g2lds16(A + (size_t)(row0 + 16 * c + srow_l) * K + colb, &smA[base + c * 512]);
    }
  };
  auto stageB = [&](int tau, int hh) {
    const int base = (((tau & 1) * 2 + hh) * 8192);
    const int colb = tau * 64 + hh * 32 + scol;
    #pragma unroll
    for (int j = 0; j < 2; ++j) {
      const int c = j * 8 + w;
      g2lds16(Bt + (size_t)(col0 + 16 * c + srow_l) * K + colb, &smB[base + c * 512]);
    }
  };

  stageA(0, 0); stageB(0, 0);
  stageA(0, 1); stageB(0, 1);
  stageA(1, 0); stageB(1, 0);
  asm volatile("s_waitcnt vmcnt(8)" ::: "memory");
  __builtin_amdgcn_sched_barrier(0);
  __builtin_amdgcn_s_barrier();

  for (int tau = 0; tau < KT; ++tau) {
    const int ab0 = (tau & 1) * 16384;
    const int ab1 = ab0 + 8192;
    bf16x8 af[8], bf0, bf1;

    // ---- P1 ----
    #pragma unroll
    for (int m = 0; m < 8; ++m)
      af[m] = *(const bf16x8*)&smA[ab0 + (wm * 128 + m * 16 + lr) * 32 + ks];
    bf0 = *(const bf16x8*)&smB[ab0 + (wn * 64 + lr) * 32 + ks];
    bf1 = *(const bf16x8*)&smB[ab0 + (wn * 64 + 16 + lr) * 32 + ks];
    if (tau + 1 < KT) stageA(tau + 1, 1);
    __builtin_amdgcn_s_barrier();
    asm volatile("s_waitcnt lgkmcnt(0)" ::: "memory");
    __builtin_amdgcn_sched_barrier(0);
    __builtin_amdgcn_s_setprio(1);
    #pragma unroll
    for (int m = 0; m < 8; ++m) {
      acc[m][0] = mfma16(af[m], bf0, acc[m][0]);
      acc[m][1] = mfma16(af[m], bf1, acc[m][1]);
    }
    __builtin_amdgcn_s_setprio(0);
    __builtin_amdgcn_s_barrier();

    // ---- P2 ----
    bf0 = *(const bf16x8*)&smB[ab0 + (wn * 64 + 32 + lr) * 32 + ks];
    bf1 = *(const bf16x8*)&smB[ab0 + (wn * 64 + 48 + lr) * 32 + ks];
    if (tau + 1 < KT) stageB(tau + 1, 1);
    __builtin_amdgcn_s_barrier();
    asm volatile("s_waitcnt lgkmcnt(0)" ::: "memory");
    __builtin_amdgcn_sched_barrier(0);
    __builtin_amdgcn_s_setprio(1);
    #pragma unroll
    for (int m = 0; m < 8; ++m) {
      acc[m][2] = mfma16(af[m], bf0, acc[m][2]);
      acc[m][3] = mfma16(af[m], bf1, acc[m][3]);
    }
    __builtin_amdgcn_s_setprio(0);
    if (tau + 1 < KT) { asm volatile("s_waitcnt vmcnt(8)" ::: "memory"); }
    else              { asm volatile("s_waitcnt vmcnt(0)" ::: "memory"); }
    __builtin_amdgcn_sched_barrier(0);
    __builtin_amdgcn_s_barrier();

    // ---- P3 ----
    #pragma unroll
    for (int m = 0; m < 8; ++m)
      af[m] = *(const bf16x8*)&smA[ab1 + (wm * 128 + m * 16 + lr) * 32 + ks];
    bf0 = *(const bf16x8*)&smB[ab1 + (wn * 64 + lr) * 32 + ks];
    bf1 = *(const bf16x8*)&smB[ab1 + (wn * 64 + 16 + lr) * 32 + ks];
    if (tau + 2 < KT) { stageA(tau + 2, 0); stageB(tau + 2, 0); }
    __builtin_amdgcn_s_barrier();
    asm volatile("s_waitcnt lgkmcnt(0)" ::: "memory");
    __builtin_amdgcn_sched_barrier(0);
    __builtin_amdgcn_s_setprio(1);
    #pragma unroll
    for (int m = 0; m < 8; ++m) {
      acc[m][0] = mfma16(af[m], bf0, acc[m][0]);
      acc[m][1] = mfma16(af[m], bf1, acc[m][1]);
    }
    __builtin_amdgcn_s_setprio(0);
    __builtin_amdgcn_s_barrier();

    // ---- P4 ----
    bf0 = *(const bf16x8*)&smB[ab1 + (wn * 64 + 32 + lr) * 32 + ks];
    bf1 = *(const bf16x8*)&smB[ab1 + (wn * 64 + 48 + lr) * 32 + ks];
    __builtin_amdgcn_s_barrier();
    asm volatile("s_waitcnt lgkmcnt(0)" ::: "memory");
    __builtin_amdgcn_sched_barrier(0);
    __builtin_amdgcn_s_setprio(1);
    #pragma unroll
    for (int m = 0; m < 8; ++m) {
      acc[m][2] = mfma16(af[m], bf0, acc[m][2]);
      acc[m][3] = mfma16(af[m], bf1, acc[m][3]);
    }
    __builtin_amdgcn_s_setprio(0);
    if (tau + 2 < KT)      { asm volatile("s_waitcnt vmcnt(8)" ::: "memory"); }
    else if (tau + 1 < KT) { asm volatile("s_waitcnt vmcnt(4)" ::: "memory"); }
    __builtin_amdgcn_sched_barrier(0);
    __builtin_amdgcn_s_barrier();
  }

  #pragma unroll
  for (int m = 0; m < 8; ++m) {
    #pragma unroll
    for (int n = 0; n < 4; ++n) {
      #pragma unroll
      for (int i = 0; i < 4; ++i) {
        const int r = row0 + wm * 128 + m * 16 + lg * 4 + i;
        const int c = col0 + wn * 64 + n * 16 + lr;
        float v = acc[m][n][i] + bias[c];
        if constexpr (EPI == EPI_QKV) {
          const int h = (unsigned)c / 192u;
          const int o = c - h * 192;
          if (o < 128) {
            outb[(size_t)r * N + c] = f2bf(v);  // Q or K -> qkvb
          } else {
            // V -> vT[((r>>10)*16+h)*64 + (o-128)][r & 1023]
            const size_t vrow = ((size_t)(r >> 10) * 16 + h) * 64 + (o - 128);
            vT[vrow * NDIM + (r & (NDIM - 1))] = f2bf(v);
          }
        } else {
          if constexpr (EPI == EPI_GELU) {
            v = 0.5f * v * (1.0f + erff(v * 0.70710678118f));
          }
          outb[(size_t)r * N + c] = f2bf(v);
        }
      }
    }
  }
}

// ---------------- 128x128 GEMM (O / PR projections, residual add) -------------
enum { GEPI_BF16 = 0, GEPI_RES = 1 };

template <int EPI>
__global__ __launch_bounds__(256) void gemm_kernel(
    const ushort* __restrict__ A, const ushort* __restrict__ Bt,
    const float* __restrict__ bias, float* __restrict__ resid,
    ushort* __restrict__ outb, int M, int N, int K) {
  __shared__ ushort smA[2][128 * 64];
  __shared__ ushort smB[2][128 * 64];
  const int tid = threadIdx.x;
  const int w = tid >> 6, l = tid & 63;
  const int lr = l & 15, lg = l >> 4;
  const int wr = (w >> 1) * 64, wc = (w & 1) * 64;

  const int gx = gridDim.x;
  const int nwg = gx * gridDim.y;
  const int id0 = blockIdx.y * gx + blockIdx.x;
  const int id = (id0 & 7) * (nwg >> 3) + (id0 >> 3);
  const int row0 = (id / gx) * 128, col0 = (id % gx) * 128;

  const int srow = tid >> 3;
  const int sslot = tid & 7;
  f32x4 acc[4][4] = {};
  const int KT = K >> 6;

  auto stage = [&](int buf, int kt) {
    const int kb = kt << 6;
    #pragma unroll
    for (int j = 0; j < 4; ++j) {
      const int r = j * 32 + srow;
      const int sc = ((sslot ^ (r & 7)) * 8);
      g2lds16(A  + (size_t)(row0 + r) * K + kb + sc, &smA[buf][j * 2048 + w * 512]);
      g2lds16(Bt + (size_t)(col0 + r) * K + kb + sc, &smB[buf][j * 2048 + w * 512]);
    }
  };

  stage(0, 0);
  int cur = 0;
  for (int kt = 0; kt < KT; ++kt) {
    __syncthreads();
    if (kt + 1 < KT) stage(cur ^ 1, kt + 1);
    bf16x8 af[2][4], bfr[2][4];
    const int rs = lr & 7;
    #pragma unroll
    for (int kk = 0; kk < 2; ++kk) {
      #pragma unroll
      for (int t = 0; t < 4; ++t) {
        const int k8 = (kk * 4 + lg) ^ rs;
        af[kk][t]  = *(const bf16x8*)&smA[cur][(wr + t * 16 + lr) * 64 + k8 * 8];
        bfr[kk][t] = *(const bf16x8*)&smB[cur][(wc + t * 16 + lr) * 64 + k8 * 8];
      }
    }
    __builtin_amdgcn_s_setprio(1);
    #pragma unroll
    for (int kk = 0; kk < 2; ++kk)
      #pragma unroll
      for (int mt = 0; mt < 4; ++mt)
        #pragma unroll
        for (int nt = 0; nt < 4; ++nt)
          acc[mt][nt] = mfma16(af[kk][mt], bfr[kk][nt], acc[mt][nt]);
    __builtin_amdgcn_s_setprio(0);
    cur ^= 1;
  }

  #pragma unroll
  for (int mt = 0; mt < 4; ++mt) {
    #pragma unroll
    for (int nt = 0; nt < 4; ++nt) {
      #pragma unroll
      for (int i = 0; i < 4; ++i) {
        const int r = row0 + wr + mt * 16 + lg * 4 + i;
        const int c = col0 + wc + nt * 16 + lr;
        float v = acc[mt][nt][i] + bias[c];
        if constexpr (EPI == GEPI_RES) {
          resid[(size_t)r * N + c] += v;
        } else {
          outb[(size_t)r * N + c] = f2bf(v);
        }
      }
    }
  }
}

// ------- fused attention: swapped QK^T, in-register P repack (no P-LDS) -------
__global__ __launch_bounds__(512) void attn_kernel(const ushort* __restrict__ qkv,
                                                   const ushort* __restrict__ vT,
                                                   ushort* __restrict__ out) {
  const int qb = blockIdx.x;
  const int bh = blockIdx.y;
  const int b = bh >> 4, h = bh & 15;
  const int tid = threadIdx.x;
  const int w = tid >> 6, l = tid & 63;
  const int lr = l & 15, lg = l >> 4;
  __shared__ ushort smK[2][64 * 64];
  __shared__ ushort smV[2][64 * 64];
  const int q0 = qb * 128 + w * 16;
  const size_t rowb = (size_t)b * NDIM;
  const ushort* vhead = vT + (size_t)bh * 64 * NDIM;  // [64][N]

  const u16x8 ob = {0x3F80, 0x3F80, 0x3F80, 0x3F80, 0x3F80, 0x3F80, 0x3F80, 0x3F80};
  const bf16x8 onesv = __builtin_bit_cast(bf16x8, ob);

  const int srow = l >> 3;
  const int skey = (srow & 3) ^ ((w & 1) << 2);
  const int scol = ((l & 7) ^ skey) * 8;
  const ushort* kg = qkv + (rowb + w * 8 + srow) * 3072 + h * 192 + 64 + scol;
  const ushort* vg = vhead + (size_t)(w * 8 + srow) * NDIM + scol;

  auto stage = [&](int buf, int kb) {
    g2lds16(kg + (size_t)kb * 64 * 3072, &smK[buf][w * 512]);
    g2lds16(vg + kb * 64,                &smV[buf][w * 512]);
  };

  bf16x8 qf0, qf1;
  {
    const ushort* qp = qkv + (rowb + q0 + lr) * 3072 + h * 192;
    qf0 = *(const bf16x8*)(qp + lg * 8);
    qf1 = *(const bf16x8*)(qp + 32 + lg * 8);
  }
  f32x4 o[4] = {};
  f32x4 lacc = {0.f, 0.f, 0.f, 0.f};

  const int rbase = (lr >> 2) * 8 + (lr & 3);
  const int kkey  = (lr & 3) ^ (((lr >> 2) & 1) << 2);
  const int vkey  = (lr & 3) ^ (((lr >> 3) & 1) << 2);
  const int kp0 = (lg ^ kkey) * 8, kp1 = ((4 + lg) ^ kkey) * 8;
  const int vp0 = (lg ^ vkey) * 8, vp1 = ((4 + lg) ^ vkey) * 8;

  stage(0, 0);
  int cur = 0;
  for (int kb = 0; kb < NDIM / 64; ++kb) {
    __syncthreads();
    if (kb + 1 < NDIM / 64) stage(cur ^ 1, kb + 1);

    f32x4 s[2][2];
    #pragma unroll
    for (int hh = 0; hh < 2; ++hh) {
      #pragma unroll
      for (int m = 0; m < 2; ++m) {
        const int r = hh * 32 + rbase + 4 * m;
        const ushort* kr = &smK[cur][r * 64];
        const bf16x8 kf0 = *(const bf16x8*)&kr[kp0];
        const bf16x8 kf1 = *(const bf16x8*)&kr[kp1];
        f32x4 z = {0.f, 0.f, 0.f, 0.f};
        s[hh][m] = mfma16(kf1, qf1, mfma16(kf0, qf0, z));
      }
    }

    bf16x8 pf[2];
    #pragma unroll
    for (int hh = 0; hh < 2; ++hh) {
      u32x4 pk;
      pk[0] = cvtpk(__expf(s[hh][0][0] * 0.125f), __expf(s[hh][0][1] * 0.125f));
      pk[1] = cvtpk(__expf(s[hh][0][2] * 0.125f), __expf(s[hh][0][3] * 0.125f));
      pk[2] = cvtpk(__expf(s[hh][1][0] * 0.125f), __expf(s[hh][1][1] * 0.125f));
      pk[3] = cvtpk(__expf(s[hh][1][2] * 0.125f), __expf(s[hh][1][3] * 0.125f));
      pf[hh] = __builtin_bit_cast(bf16x8, pk);
    }

    lacc = mfma16(pf[0], onesv, mfma16(pf[1], onesv, lacc));
    #pragma unroll
    for (int dt = 0; dt < 4; ++dt) {
      const ushort* vrow = &smV[cur][(dt * 16 + lr) * 64];
      const bf16x8 vf0 = *(const bf16x8*)&vrow[vp0];
      const bf16x8 vf1 = *(const bf16x8*)&vrow[vp1];
      o[dt] = mfma16(pf[0], vf0, mfma16(pf[1], vf1, o[dt]));
    }
    cur ^= 1;
  }

  #pragma unroll
  for (int i = 0; i < 4; ++i) {
    const float inv = 1.0f / lacc[i];
    const size_t orow = (rowb + q0 + lg * 4 + i) * (size_t)WDIM;
    #pragma unroll
    for (int dt = 0; dt < 4; ++dt)
      out[orow + h * 64 + dt * 16 + lr] = f2bf(o[dt][i] * inv);
  }
}

// ------------------------------- launcher ------------------------------------
extern "C" void kernel_launch(void* const* d_in, const int* in_sizes, int n_in,
                              void* d_out, int out_size, void* d_ws, size_t ws_size,
                              hipStream_t stream) {
  const float* x     = (const float*)d_in[0];
  const float* ln1_g = (const float*)d_in[1];
  const float* ln1_b = (const float*)d_in[2];
  const float* w_qkv = (const float*)d_in[3];
  const float* b_qkv = (const float*)d_in[4];
  const float* w_o   = (const float*)d_in[5];
  const float* b_o   = (const float*)d_in[6];
  const float* ln2_g = (const float*)d_in[7];
  const float* ln2_b = (const float*)d_in[8];
  const float* w_fc  = (const float*)d_in[9];
  const float* b_fc  = (const float*)d_in[10];
  const float* w_pr  = (const float*)d_in[11];
  const float* b_pr  = (const float*)d_in[12];

  float* hbuf = (float*)d_out;  // fp32 residual stream lives in d_out

  uint8_t* p = (uint8_t*)d_ws;
  ushort* wqkv_t = (ushort*)p; p += (size_t)3072 * 1024 * 2;
  ushort* wo_t   = (ushort*)p; p += (size_t)1024 * 1024 * 2;
  ushort* wfc_t  = (ushort*)p; p += (size_t)4096 * 1024 * 2;
  ushort* wpr_t  = (ushort*)p; p += (size_t)1024 * 4096 * 2;
  ushort* lnb    = (ushort*)p; p += (size_t)MROWS * 1024 * 2;
  ushort* qkvb   = (ushort*)p; p += (size_t)MROWS * 3072 * 2;
  ushort* attnb  = (ushort*)p; p += (size_t)MROWS * 1024 * 2;
  ushort* mlpb   = (ushort*)p; p += (size_t)MROWS * 4096 * 2;
  ushort* vTb    = (ushort*)p; p += (size_t)BDIM * HDIM * 64 * NDIM * 2;

  hipMemcpyAsync(hbuf, x, (size_t)MROWS * WDIM * sizeof(float),
                 hipMemcpyDeviceToDevice, stream);

  for (int l = 0; l < LDIM; ++l) {
    // ---- attention half ----
    ln_kernel<<<MROWS / 4, 256, 0, stream>>>(hbuf, ln1_g + l * 1024, ln1_b + l * 1024, lnb);
    transpose_cvt<<<dim3(96, 32), dim3(32, 8), 0, stream>>>(
        w_qkv + (size_t)l * 1024 * 3072, wqkv_t, 1024, 3072);
    gemm256_kernel<EPI_QKV><<<dim3(12, 32), 512, 0, stream>>>(
        lnb, wqkv_t, b_qkv + (size_t)l * 3072, vTb, qkvb, MROWS, 3072, 1024);
    attn_kernel<<<dim3(8, 128), 512, 0, stream>>>(qkvb, vTb, attnb);
    transpose_cvt<<<dim3(32, 32), dim3(32, 8), 0, stream>>>(
        w_o + (size_t)l * 1024 * 1024, wo_t, 1024, 1024);
    gemm_kernel<GEPI_RES><<<dim3(8, 64), 256, 0, stream>>>(
        attnb, wo_t, b_o + (size_t)l * 1024, hbuf, nullptr, MROWS, 1024, 1024);
    // ---- MLP half ----
    ln_kernel<<<MROWS / 4, 256, 0, stream>>>(hbuf, ln2_g + l * 1024, ln2_b + l * 1024, lnb);
    transpose_cvt<<<dim3(128, 32), dim3(32, 8), 0, stream>>>(
        w_fc + (size_t)l * 1024 * 4096, wfc_t, 1024, 4096);
    gemm256_kernel<EPI_GELU><<<dim3(16, 32), 512, 0, stream>>>(
        lnb, wfc_t, b_fc + (size_t)l * 4096, nullptr, mlpb, MROWS, 4096, 1024);
    transpose_cvt<<<dim3(32, 128), dim3(32, 8), 0, stream>>>(
        w_pr + (size_t)l * 4096 * 1024, wpr_t, 4096, 1024);
    gemm_kernel<GEPI_RES><<<dim3(8, 64), 256, 0, stream>>>(
        mlpb, wpr_t, b_pr + (size_t)l * 1024, hbuf, nullptr, MROWS, 1024, 4096);
  }
}

// Round 13
// 4419.334 us; speedup vs baseline: 1.2013x; 1.0459x over previous
//
#include <hip/hip_runtime.h>
#include <cstdint>
#include <cstddef>

// Problem dims (fixed by reference)
#define WDIM 1024
#define BDIM 8
#define NDIM 1024
#define LDIM 12
#define HDIM 16
#define MROWS (BDIM * NDIM)   // 8192 token rows

using bf16x8 = __attribute__((ext_vector_type(8))) __bf16;
using f32x4  = __attribute__((ext_vector_type(4))) float;
using u32x4  = __attribute__((ext_vector_type(4))) uint32_t;
using u16x8  = __attribute__((ext_vector_type(8))) ushort;

static __device__ __forceinline__ f32x4 mfma16(bf16x8 a, bf16x8 b, f32x4 c) {
  return __builtin_amdgcn_mfma_f32_16x16x32_bf16(a, b, c, 0, 0, 0);
}

// fp32 -> bf16 round-to-nearest-even
static __device__ __forceinline__ ushort f2bf(float f) {
  uint32_t u = __builtin_bit_cast(uint32_t, f);
  u = (u + 0x7FFFu + ((u >> 16) & 1u)) >> 16;
  return (ushort)u;
}

static __device__ __forceinline__ uint32_t cvtpk(float lo, float hi) {
  uint32_t r;
  asm("v_cvt_pk_bf16_f32 %0, %1, %2" : "=v"(r) : "v"(lo), "v"(hi));
  return r;
}

// async global->LDS, 16B per lane; LDS dest must be wave-uniform base (lane*16 auto)
static __device__ __forceinline__ void g2lds16(const void* g, void* l) {
  __builtin_amdgcn_global_load_lds(
      (__attribute__((address_space(1))) void*)(g),
      (__attribute__((address_space(3))) void*)(l), 16, 0, 0);
}

// -------- LayerNorm: wave-per-row, 4 rows/block, no LDS, no barrier ----------
__global__ __launch_bounds__(256) void ln_kernel(const float* __restrict__ h,
                                                 const float* __restrict__ g,
                                                 const float* __restrict__ b,
                                                 ushort* __restrict__ out) {
  const int w = threadIdx.x >> 6, l = threadIdx.x & 63;
  const int row = blockIdx.x * 4 + w;
  const float4* rp = (const float4*)(h + (size_t)row * WDIM);
  float4 v[4];
  float s = 0.f, s2 = 0.f;
  #pragma unroll
  for (int j = 0; j < 4; ++j) {
    v[j] = rp[j * 64 + l];
    s  += v[j].x + v[j].y + v[j].z + v[j].w;
    s2 += v[j].x * v[j].x + v[j].y * v[j].y + v[j].z * v[j].z + v[j].w * v[j].w;
  }
  #pragma unroll
  for (int off = 32; off; off >>= 1) {
    s  += __shfl_xor(s, off);
    s2 += __shfl_xor(s2, off);
  }
  const float mu   = s * (1.0f / WDIM);
  const float var  = s2 * (1.0f / WDIM) - mu * mu;
  const float rstd = rsqrtf(var + 1e-5f);
  ushort4* op = (ushort4*)(out + (size_t)row * WDIM);
  #pragma unroll
  for (int j = 0; j < 4; ++j) {
    const float4 gv = ((const float4*)g)[j * 64 + l];
    const float4 bv = ((const float4*)b)[j * 64 + l];
    ushort4 o;
    o.x = f2bf((v[j].x - mu) * rstd * gv.x + bv.x);
    o.y = f2bf((v[j].y - mu) * rstd * gv.y + bv.y);
    o.z = f2bf((v[j].z - mu) * rstd * gv.z + bv.z);
    o.w = f2bf((v[j].w - mu) * rstd * gv.w + bv.w);
    op[j * 64 + l] = o;
  }
}

// ------ weight transpose+convert: fp32 [K][N] -> bf16 [N][K], 64x64 tiles -----
// float4 loads, uint4 stores; LDS [64][65] (+1 pad -> 2-way aliasing, free).
__global__ __launch_bounds__(256) void transpose_cvt(const float* __restrict__ in,
                                                     ushort* __restrict__ out,
                                                     int K, int N) {
  __shared__ float sm[64][65];
  const int n0 = blockIdx.x * 64, k0 = blockIdx.y * 64;
  const int t = threadIdx.x;
  const int lk = t >> 4;          // 0..15
  const int ln4 = (t & 15) * 4;   // 0,4,..,60
  #pragma unroll
  for (int j = 0; j < 4; ++j) {
    const float4 v = *(const float4*)&in[(size_t)(k0 + j * 16 + lk) * N + n0 + ln4];
    sm[j * 16 + lk][ln4 + 0] = v.x;
    sm[j * 16 + lk][ln4 + 1] = v.y;
    sm[j * 16 + lk][ln4 + 2] = v.z;
    sm[j * 16 + lk][ln4 + 3] = v.w;
  }
  __syncthreads();
  const int n  = t >> 2;          // 0..63
  const int ks = (t & 3) * 16;    // 0,16,32,48
  ushort tmp[16];
  #pragma unroll
  for (int j = 0; j < 16; ++j) tmp[j] = f2bf(sm[ks + j][n]);
  ushort* op = &out[(size_t)(n0 + n) * K + k0 + ks];
  *(uint4*)&op[0] = *(const uint4*)&tmp[0];
  *(uint4*)&op[8] = *(const uint4*)&tmp[8];
}

// --------- V transpose: qkv [rows][3072] -> vT [b,h,d=64,N] (bf16) -----------
__global__ __launch_bounds__(256) void v_transpose(const ushort* __restrict__ qkv,
                                                   ushort* __restrict__ vT) {
  const int nb = blockIdx.x, bh = blockIdx.y;
  const int b = bh >> 4, h = bh & 15;
  const int tid = threadIdx.x;
  __shared__ ushort smT[64 * 64];
  const int n0 = nb * 64;
  const size_t rowb = (size_t)b * NDIM;
  #pragma unroll
  for (int p = 0; p < 2; ++p) {
    const int n  = p * 32 + (tid >> 3);
    const int d0 = (tid & 7) * 8;
    const uint4 vv = *(const uint4*)(qkv + (rowb + n0 + n) * 3072 + h * 192 + 128 + d0);
    const ushort* e = (const ushort*)&vv;
    const int key = d0;
    #pragma unroll
    for (int j = 0; j < 8; ++j)
      smT[(d0 + j) * 64 + (n ^ key)] = e[j];
  }
  __syncthreads();
  #pragma unroll
  for (int p = 0; p < 2; ++p) {
    const int d  = p * 32 + (tid >> 3);
    const int nc = (tid & 7) * 8;
    const int key = (d >> 3) << 3;
    const uint4 ov = *(const uint4*)&smT[d * 64 + (nc ^ key)];
    *(uint4*)(vT + ((size_t)bh * 64 + d) * NDIM + n0 + nc) = ov;
  }
}

// =================== 256x256 8-phase GEMM (QKV / FC only) ====================
enum { EPI_BF16 = 0, EPI_GELU = 2 };

template <int EPI>
__global__ __launch_bounds__(512, 2) void gemm256_kernel(
    const ushort* __restrict__ A, const ushort* __restrict__ Bt,
    const float* __restrict__ bias, ushort* __restrict__ outb,
    int M, int N, int K) {
  __shared__ ushort smA[2 * 2 * 256 * 32];
  __shared__ ushort smB[2 * 2 * 256 * 32];
  const int tid = threadIdx.x;
  const int w = tid >> 6, l = tid & 63;
  const int lr = l & 15, lg = l >> 4;
  const int wm = w >> 2, wn = w & 3;

  const int gx = gridDim.x;
  const int nwg = gx * gridDim.y;
  const int id0 = blockIdx.y * gx + blockIdx.x;
  const int id = (id0 & 7) * (nwg >> 3) + (id0 >> 3);
  const int row0 = (id / gx) * 256, col0 = (id % gx) * 256;

  const int KT = K >> 6;
  const int srow_l = l >> 2;
  const int scol = (((l & 3) ^ ((l >> 3) & 3)) * 8);
  const int ks = ((lg ^ ((lr >> 1) & 3)) * 8);

  f32x4 acc[8][4] = {};

  auto stageA = [&](int tau, int hh) {
    const int base = (((tau & 1) * 2 + hh) * 8192);
    const int colb = tau * 64 + hh * 32 + scol;
    #pragma unroll
    for (int j = 0; j < 2; ++j) {
      const int c = j * 8 + w;
      g2lds16(A + (size_t)(row0 + 16 * c + srow_l) * K + colb, &smA[base + c * 512]);
    }
  };
  auto stageB = [&](int tau, int hh) {
    const int base = (((tau & 1) * 2 + hh) * 8192);
    const int colb = tau * 64 + hh * 32 + scol;
    #pragma unroll
    for (int j = 0; j < 2; ++j) {
      const int c = j * 8 + w;
      g2lds16(Bt + (size_t)(col0 + 16 * c + srow_l) * K + colb, &smB[base + c * 512]);
    }
  };

  stageA(0, 0); stageB(0, 0);
  stageA(0, 1); stageB(0, 1);
  stageA(1, 0); stageB(1, 0);
  asm volatile("s_waitcnt vmcnt(8)" ::: "memory");
  __builtin_amdgcn_sched_barrier(0);
  __builtin_amdgcn_s_barrier();

  for (int tau = 0; tau < KT; ++tau) {
    const int ab0 = (tau & 1) * 16384;
    const int ab1 = ab0 + 8192;
    bf16x8 af[8], bf0, bf1;

    // ---- P1 ----
    #pragma unroll
    for (int m = 0; m < 8; ++m)
      af[m] = *(const bf16x8*)&smA[ab0 + (wm * 128 + m * 16 + lr) * 32 + ks];
    bf0 = *(const bf16x8*)&smB[ab0 + (wn * 64 + lr) * 32 + ks];
    bf1 = *(const bf16x8*)&smB[ab0 + (wn * 64 + 16 + lr) * 32 + ks];
    if (tau + 1 < KT) stageA(tau + 1, 1);
    __builtin_amdgcn_s_barrier();
    asm volatile("s_waitcnt lgkmcnt(0)" ::: "memory");
    __builtin_amdgcn_sched_barrier(0);
    __builtin_amdgcn_s_setprio(1);
    #pragma unroll
    for (int m = 0; m < 8; ++m) {
      acc[m][0] = mfma16(af[m], bf0, acc[m][0]);
      acc[m][1] = mfma16(af[m], bf1, acc[m][1]);
    }
    __builtin_amdgcn_s_setprio(0);
    __builtin_amdgcn_s_barrier();

    // ---- P2 ----
    bf0 = *(const bf16x8*)&smB[ab0 + (wn * 64 + 32 + lr) * 32 + ks];
    bf1 = *(const bf16x8*)&smB[ab0 + (wn * 64 + 48 + lr) * 32 + ks];
    if (tau + 1 < KT) stageB(tau + 1, 1);
    __builtin_amdgcn_s_barrier();
    asm volatile("s_waitcnt lgkmcnt(0)" ::: "memory");
    __builtin_amdgcn_sched_barrier(0);
    __builtin_amdgcn_s_setprio(1);
    #pragma unroll
    for (int m = 0; m < 8; ++m) {
      acc[m][2] = mfma16(af[m], bf0, acc[m][2]);
      acc[m][3] = mfma16(af[m], bf1, acc[m][3]);
    }
    __builtin_amdgcn_s_setprio(0);
    if (tau + 1 < KT) { asm volatile("s_waitcnt vmcnt(8)" ::: "memory"); }
    else              { asm volatile("s_waitcnt vmcnt(0)" ::: "memory"); }
    __builtin_amdgcn_sched_barrier(0);
    __builtin_amdgcn_s_barrier();

    // ---- P3 ----
    #pragma unroll
    for (int m = 0; m < 8; ++m)
      af[m] = *(const bf16x8*)&smA[ab1 + (wm * 128 + m * 16 + lr) * 32 + ks];
    bf0 = *(const bf16x8*)&smB[ab1 + (wn * 64 + lr) * 32 + ks];
    bf1 = *(const bf16x8*)&smB[ab1 + (wn * 64 + 16 + lr) * 32 + ks];
    if (tau + 2 < KT) { stageA(tau + 2, 0); stageB(tau + 2, 0); }
    __builtin_amdgcn_s_barrier();
    asm volatile("s_waitcnt lgkmcnt(0)" ::: "memory");
    __builtin_amdgcn_sched_barrier(0);
    __builtin_amdgcn_s_setprio(1);
    #pragma unroll
    for (int m = 0; m < 8; ++m) {
      acc[m][0] = mfma16(af[m], bf0, acc[m][0]);
      acc[m][1] = mfma16(af[m], bf1, acc[m][1]);
    }
    __builtin_amdgcn_s_setprio(0);
    __builtin_amdgcn_s_barrier();

    // ---- P4 ----
    bf0 = *(const bf16x8*)&smB[ab1 + (wn * 64 + 32 + lr) * 32 + ks];
    bf1 = *(const bf16x8*)&smB[ab1 + (wn * 64 + 48 + lr) * 32 + ks];
    __builtin_amdgcn_s_barrier();
    asm volatile("s_waitcnt lgkmcnt(0)" ::: "memory");
    __builtin_amdgcn_sched_barrier(0);
    __builtin_amdgcn_s_setprio(1);
    #pragma unroll
    for (int m = 0; m < 8; ++m) {
      acc[m][2] = mfma16(af[m], bf0, acc[m][2]);
      acc[m][3] = mfma16(af[m], bf1, acc[m][3]);
    }
    __builtin_amdgcn_s_setprio(0);
    if (tau + 2 < KT)      { asm volatile("s_waitcnt vmcnt(8)" ::: "memory"); }
    else if (tau + 1 < KT) { asm volatile("s_waitcnt vmcnt(4)" ::: "memory"); }
    __builtin_amdgcn_sched_barrier(0);
    __builtin_amdgcn_s_barrier();
  }

  #pragma unroll
  for (int m = 0; m < 8; ++m) {
    #pragma unroll
    for (int n = 0; n < 4; ++n) {
      #pragma unroll
      for (int i = 0; i < 4; ++i) {
        const int r = row0 + wm * 128 + m * 16 + lg * 4 + i;
        const int c = col0 + wn * 64 + n * 16 + lr;
        float v = acc[m][n][i] + bias[c];
        if constexpr (EPI == EPI_GELU) {
          v = 0.5f * v * (1.0f + erff(v * 0.70710678118f));
        }
        outb[(size_t)r * N + c] = f2bf(v);
      }
    }
  }
}

// ---------------- 128x128 GEMM (O / PR projections, residual add) -------------
enum { GEPI_BF16 = 0, GEPI_RES = 1 };

template <int EPI>
__global__ __launch_bounds__(256) void gemm_kernel(
    const ushort* __restrict__ A, const ushort* __restrict__ Bt,
    const float* __restrict__ bias, float* __restrict__ resid,
    ushort* __restrict__ outb, int M, int N, int K) {
  __shared__ ushort smA[2][128 * 64];
  __shared__ ushort smB[2][128 * 64];
  const int tid = threadIdx.x;
  const int w = tid >> 6, l = tid & 63;
  const int lr = l & 15, lg = l >> 4;
  const int wr = (w >> 1) * 64, wc = (w & 1) * 64;

  const int gx = gridDim.x;
  const int nwg = gx * gridDim.y;
  const int id0 = blockIdx.y * gx + blockIdx.x;
  const int id = (id0 & 7) * (nwg >> 3) + (id0 >> 3);
  const int row0 = (id / gx) * 128, col0 = (id % gx) * 128;

  const int srow = tid >> 3;
  const int sslot = tid & 7;
  f32x4 acc[4][4] = {};
  const int KT = K >> 6;

  auto stage = [&](int buf, int kt) {
    const int kb = kt << 6;
    #pragma unroll
    for (int j = 0; j < 4; ++j) {
      const int r = j * 32 + srow;
      const int sc = ((sslot ^ (r & 7)) * 8);
      g2lds16(A  + (size_t)(row0 + r) * K + kb + sc, &smA[buf][j * 2048 + w * 512]);
      g2lds16(Bt + (size_t)(col0 + r) * K + kb + sc, &smB[buf][j * 2048 + w * 512]);
    }
  };

  stage(0, 0);
  int cur = 0;
  for (int kt = 0; kt < KT; ++kt) {
    __syncthreads();
    if (kt + 1 < KT) stage(cur ^ 1, kt + 1);
    bf16x8 af[2][4], bfr[2][4];
    const int rs = lr & 7;
    #pragma unroll
    for (int kk = 0; kk < 2; ++kk) {
      #pragma unroll
      for (int t = 0; t < 4; ++t) {
        const int k8 = (kk * 4 + lg) ^ rs;
        af[kk][t]  = *(const bf16x8*)&smA[cur][(wr + t * 16 + lr) * 64 + k8 * 8];
        bfr[kk][t] = *(const bf16x8*)&smB[cur][(wc + t * 16 + lr) * 64 + k8 * 8];
      }
    }
    __builtin_amdgcn_s_setprio(1);
    #pragma unroll
    for (int kk = 0; kk < 2; ++kk)
      #pragma unroll
      for (int mt = 0; mt < 4; ++mt)
        #pragma unroll
        for (int nt = 0; nt < 4; ++nt)
          acc[mt][nt] = mfma16(af[kk][mt], bfr[kk][nt], acc[mt][nt]);
    __builtin_amdgcn_s_setprio(0);
    cur ^= 1;
  }

  #pragma unroll
  for (int mt = 0; mt < 4; ++mt) {
    #pragma unroll
    for (int nt = 0; nt < 4; ++nt) {
      #pragma unroll
      for (int i = 0; i < 4; ++i) {
        const int r = row0 + wr + mt * 16 + lg * 4 + i;
        const int c = col0 + wc + nt * 16 + lr;
        float v = acc[mt][nt][i] + bias[c];
        if constexpr (EPI == GEPI_RES) {
          resid[(size_t)r * N + c] += v;
        } else {
          outb[(size_t)r * N + c] = f2bf(v);
        }
      }
    }
  }
}

// ------- fused attention: swapped QK^T, in-register P repack (no P-LDS) -------
__global__ __launch_bounds__(512) void attn_kernel(const ushort* __restrict__ qkv,
                                                   const ushort* __restrict__ vT,
                                                   ushort* __restrict__ out) {
  const int qb = blockIdx.x;
  const int bh = blockIdx.y;
  const int b = bh >> 4, h = bh & 15;
  const int tid = threadIdx.x;
  const int w = tid >> 6, l = tid & 63;
  const int lr = l & 15, lg = l >> 4;
  __shared__ ushort smK[2][64 * 64];
  __shared__ ushort smV[2][64 * 64];
  const int q0 = qb * 128 + w * 16;
  const size_t rowb = (size_t)b * NDIM;
  const ushort* vhead = vT + (size_t)bh * 64 * NDIM;  // [64][N]

  const u16x8 ob = {0x3F80, 0x3F80, 0x3F80, 0x3F80, 0x3F80, 0x3F80, 0x3F80, 0x3F80};
  const bf16x8 onesv = __builtin_bit_cast(bf16x8, ob);

  const int srow = l >> 3;
  const int skey = (srow & 3) ^ ((w & 1) << 2);
  const int scol = ((l & 7) ^ skey) * 8;
  const ushort* kg = qkv + (rowb + w * 8 + srow) * 3072 + h * 192 + 64 + scol;
  const ushort* vg = vhead + (size_t)(w * 8 + srow) * NDIM + scol;

  auto stage = [&](int buf, int kb) {
    g2lds16(kg + (size_t)kb * 64 * 3072, &smK[buf][w * 512]);
    g2lds16(vg + kb * 64,                &smV[buf][w * 512]);
  };

  bf16x8 qf0, qf1;
  {
    const ushort* qp = qkv + (rowb + q0 + lr) * 3072 + h * 192;
    qf0 = *(const bf16x8*)(qp + lg * 8);
    qf1 = *(const bf16x8*)(qp + 32 + lg * 8);
  }
  f32x4 o[4] = {};
  f32x4 lacc = {0.f, 0.f, 0.f, 0.f};

  const int rbase = (lr >> 2) * 8 + (lr & 3);
  const int kkey  = (lr & 3) ^ (((lr >> 2) & 1) << 2);
  const int vkey  = (lr & 3) ^ (((lr >> 3) & 1) << 2);
  const int kp0 = (lg ^ kkey) * 8, kp1 = ((4 + lg) ^ kkey) * 8;
  const int vp0 = (lg ^ vkey) * 8, vp1 = ((4 + lg) ^ vkey) * 8;

  stage(0, 0);
  int cur = 0;
  for (int kb = 0; kb < NDIM / 64; ++kb) {
    __syncthreads();
    if (kb + 1 < NDIM / 64) stage(cur ^ 1, kb + 1);

    f32x4 s[2][2];
    __builtin_amdgcn_s_setprio(1);
    #pragma unroll
    for (int hh = 0; hh < 2; ++hh) {
      #pragma unroll
      for (int m = 0; m < 2; ++m) {
        const int r = hh * 32 + rbase + 4 * m;
        const ushort* kr = &smK[cur][r * 64];
        const bf16x8 kf0 = *(const bf16x8*)&kr[kp0];
        const bf16x8 kf1 = *(const bf16x8*)&kr[kp1];
        f32x4 z = {0.f, 0.f, 0.f, 0.f};
        s[hh][m] = mfma16(kf1, qf1, mfma16(kf0, qf0, z));
      }
    }
    __builtin_amdgcn_s_setprio(0);

    bf16x8 pf[2];
    #pragma unroll
    for (int hh = 0; hh < 2; ++hh) {
      u32x4 pk;
      pk[0] = cvtpk(__expf(s[hh][0][0] * 0.125f), __expf(s[hh][0][1] * 0.125f));
      pk[1] = cvtpk(__expf(s[hh][0][2] * 0.125f), __expf(s[hh][0][3] * 0.125f));
      pk[2] = cvtpk(__expf(s[hh][1][0] * 0.125f), __expf(s[hh][1][1] * 0.125f));
      pk[3] = cvtpk(__expf(s[hh][1][2] * 0.125f), __expf(s[hh][1][3] * 0.125f));
      pf[hh] = __builtin_bit_cast(bf16x8, pk);
    }

    __builtin_amdgcn_s_setprio(1);
    lacc = mfma16(pf[0], onesv, mfma16(pf[1], onesv, lacc));
    #pragma unroll
    for (int dt = 0; dt < 4; ++dt) {
      const ushort* vrow = &smV[cur][(dt * 16 + lr) * 64];
      const bf16x8 vf0 = *(const bf16x8*)&vrow[vp0];
      const bf16x8 vf1 = *(const bf16x8*)&vrow[vp1];
      o[dt] = mfma16(pf[0], vf0, mfma16(pf[1], vf1, o[dt]));
    }
    __builtin_amdgcn_s_setprio(0);
    cur ^= 1;
  }

  #pragma unroll
  for (int i = 0; i < 4; ++i) {
    const float inv = 1.0f / lacc[i];
    const size_t orow = (rowb + q0 + lg * 4 + i) * (size_t)WDIM;
    #pragma unroll
    for (int dt = 0; dt < 4; ++dt)
      out[orow + h * 64 + dt * 16 + lr] = f2bf(o[dt][i] * inv);
  }
}

// ------------------------------- launcher ------------------------------------
extern "C" void kernel_launch(void* const* d_in, const int* in_sizes, int n_in,
                              void* d_out, int out_size, void* d_ws, size_t ws_size,
                              hipStream_t stream) {
  const float* x     = (const float*)d_in[0];
  const float* ln1_g = (const float*)d_in[1];
  const float* ln1_b = (const float*)d_in[2];
  const float* w_qkv = (const float*)d_in[3];
  const float* b_qkv = (const float*)d_in[4];
  const float* w_o   = (const float*)d_in[5];
  const float* b_o   = (const float*)d_in[6];
  const float* ln2_g = (const float*)d_in[7];
  const float* ln2_b = (const float*)d_in[8];
  const float* w_fc  = (const float*)d_in[9];
  const float* b_fc  = (const float*)d_in[10];
  const float* w_pr  = (const float*)d_in[11];
  const float* b_pr  = (const float*)d_in[12];

  float* hbuf = (float*)d_out;  // fp32 residual stream lives in d_out

  uint8_t* p = (uint8_t*)d_ws;
  ushort* wqkv_t = (ushort*)p; p += (size_t)3072 * 1024 * 2;
  ushort* wo_t   = (ushort*)p; p += (size_t)1024 * 1024 * 2;
  ushort* wfc_t  = (ushort*)p; p += (size_t)4096 * 1024 * 2;
  ushort* wpr_t  = (ushort*)p; p += (size_t)1024 * 4096 * 2;
  ushort* lnb    = (ushort*)p; p += (size_t)MROWS * 1024 * 2;
  ushort* qkvb   = (ushort*)p; p += (size_t)MROWS * 3072 * 2;
  ushort* attnb  = (ushort*)p; p += (size_t)MROWS * 1024 * 2;
  ushort* mlpb   = (ushort*)p; p += (size_t)MROWS * 4096 * 2;
  ushort* vTb    = (ushort*)p; p += (size_t)BDIM * HDIM * 64 * NDIM * 2;

  hipMemcpyAsync(hbuf, x, (size_t)MROWS * WDIM * sizeof(float),
                 hipMemcpyDeviceToDevice, stream);

  for (int l = 0; l < LDIM; ++l) {
    // ---- attention half ----
    ln_kernel<<<MROWS / 4, 256, 0, stream>>>(hbuf, ln1_g + l * 1024, ln1_b + l * 1024, lnb);
    transpose_cvt<<<dim3(48, 16), 256, 0, stream>>>(
        w_qkv + (size_t)l * 1024 * 3072, wqkv_t, 1024, 3072);
    gemm256_kernel<EPI_BF16><<<dim3(12, 32), 512, 0, stream>>>(
        lnb, wqkv_t, b_qkv + (size_t)l * 3072, qkvb, MROWS, 3072, 1024);
    v_transpose<<<dim3(16, 128), 256, 0, stream>>>(qkvb, vTb);
    attn_kernel<<<dim3(8, 128), 512, 0, stream>>>(qkvb, vTb, attnb);
    transpose_cvt<<<dim3(16, 16), 256, 0, stream>>>(
        w_o + (size_t)l * 1024 * 1024, wo_t, 1024, 1024);
    gemm_kernel<GEPI_RES><<<dim3(8, 64), 256, 0, stream>>>(
        attnb, wo_t, b_o + (size_t)l * 1024, hbuf, nullptr, MROWS, 1024, 1024);
    // ---- MLP half ----
    ln_kernel<<<MROWS / 4, 256, 0, stream>>>(hbuf, ln2_g + l * 1024, ln2_b + l * 1024, lnb);
    transpose_cvt<<<dim3(64, 16), 256, 0, stream>>>(
        w_fc + (size_t)l * 1024 * 4096, wfc_t, 1024, 4096);
    gemm256_kernel<EPI_GELU><<<dim3(16, 32), 512, 0, stream>>>(
        lnb, wfc_t, b_fc + (size_t)l * 4096, mlpb, MROWS, 4096, 1024);
    transpose_cvt<<<dim3(16, 64), 256, 0, stream>>>(
        w_pr + (size_t)l * 4096 * 1024, wpr_t, 4096, 1024);
    gemm_kernel<GEPI_RES><<<dim3(8, 64), 256, 0, stream>>>(
        mlpb, wpr_t, b_pr + (size_t)l * 1024, hbuf, nullptr, MROWS, 1024, 4096);
  }
}